// Round 1
// baseline (21102.757 us; speedup 1.0000x reference)
//
#include <hip/hip_runtime.h>
#include <hip/hip_bf16.h>

#define NROWS 4096    // B*S
#define DDIM  1024
#define MKEYS 32768
#define HDIM  128
#define KSEL  16

constexpr int BM = 32, BN = 512, BK = 16, LDK = 20;  // LDK=20: pad 16->20 floats, conflict-free b128 LDS reads
#define NKB (MKEYS / BN)   // 64 key blocks

__device__ __forceinline__ float bf2f(unsigned short u) {
    union { unsigned int i; float f; } x; x.i = ((unsigned int)u) << 16; return x.f;
}

// ---------------- Kernel A: sims = Q @ K^T with fused per-(row, keyblock) top-16 ----------------
// grid (NROWS/BM, MKEYS/BN); rows on x so consecutive blocks reuse the same K-tile (L2 locality).
// 256 thr: lane=tid&63, tr=tid>>6. acc[i][j] -> row row0+tr+4i, key key0+lane+64j.
__global__ __launch_bounds__(256)
void sims_topk_kernel(const float* __restrict__ Q, const float* __restrict__ K,
                      float* __restrict__ cand_val, int* __restrict__ cand_idx)
{
    __shared__ float Qs[BM][LDK];
    __shared__ float Ks[BN][LDK];
    const int tid  = threadIdx.x;
    const int lane = tid & 63;
    const int tr   = tid >> 6;
    const int row0 = blockIdx.x * BM;
    const int key0 = blockIdx.y * BN;

    float acc[8][8];
#pragma unroll
    for (int i = 0; i < 8; ++i)
#pragma unroll
        for (int j = 0; j < 8; ++j) acc[i][j] = 0.f;

    const int c4 = (tid & 3) * 4;   // k-offset within tile
    const int rk = tid >> 2;        // 0..63
    const float* Kb = K + (size_t)key0 * DDIM;
    const float* Qb = Q + (size_t)row0 * DDIM;

    for (int k0 = 0; k0 < DDIM; k0 += BK) {
        float4 kreg[8];
#pragma unroll
        for (int m = 0; m < 8; ++m)
            kreg[m] = *(const float4*)(Kb + (size_t)(rk + 64 * m) * DDIM + k0 + c4);
        float4 qreg;
        if (tid < 128)
            qreg = *(const float4*)(Qb + (size_t)rk * DDIM + k0 + c4);
        __syncthreads();   // previous iteration's LDS reads done
#pragma unroll
        for (int m = 0; m < 8; ++m)
            *(float4*)&Ks[rk + 64 * m][c4] = kreg[m];
        if (tid < 128)
            *(float4*)&Qs[rk][c4] = qreg;
        __syncthreads();
#pragma unroll
        for (int kc = 0; kc < BK; kc += 4) {
            float4 qf[8];
#pragma unroll
            for (int i = 0; i < 8; ++i) qf[i] = *(const float4*)&Qs[tr + 4 * i][kc];  // wave-broadcast
#pragma unroll
            for (int j = 0; j < 8; ++j) {
                float4 kf = *(const float4*)&Ks[lane + 64 * j][kc];
#pragma unroll
                for (int i = 0; i < 8; ++i)
                    acc[i][j] += qf[i].x * kf.x + qf[i].y * kf.y + qf[i].z * kf.z + qf[i].w * kf.w;
            }
        }
    }

    // per-row top-16 within this 512-key block (wave tr owns rows tr+4i; row spread over 64 lanes x 8 j)
#pragma unroll 1
    for (int i = 0; i < 8; ++i) {
        float v[8]; int ci[8];
#pragma unroll
        for (int j = 0; j < 8; ++j) { v[j] = acc[i][j]; ci[j] = key0 + lane + 64 * j; }
        float wval = 0.f; int widx = 0;
#pragma unroll 1
        for (int it = 0; it < KSEL; ++it) {
            float bv = v[0]; int bj = 0;
#pragma unroll
            for (int j = 1; j < 8; ++j) if (v[j] > bv) { bv = v[j]; bj = j; }  // strict > : smaller idx wins ties
            float rv = bv; int ridx = ci[bj];
#pragma unroll
            for (int off = 32; off >= 1; off >>= 1) {
                float ov = __shfl_xor(rv, off);
                int   oi = __shfl_xor(ridx, off);
                if (ov > rv || (ov == rv && oi < ridx)) { rv = ov; ridx = oi; }
            }
            if (lane == it) { wval = rv; widx = ridx; }
            if (ci[bj] == ridx) v[bj] = -__builtin_inff();   // indices unique per lane -> only winner matches
        }
        const int row = row0 + tr + 4 * i;
        if (lane < KSEL) {
            const size_t o = ((size_t)row * NKB + blockIdx.y) * KSEL + lane;
            cand_val[o] = wval;
            cand_idx[o] = widx;
        }
    }
}

// ---------------- Kernel B: merge 64 blocks x 16 candidates -> top-16 indices per row ----------------
__global__ __launch_bounds__(256)
void topk_merge_kernel(const float* __restrict__ cand_val, const int* __restrict__ cand_idx,
                       int* __restrict__ topk)
{
    const int row  = blockIdx.x * 4 + (threadIdx.x >> 6);
    const int lane = threadIdx.x & 63;
    float v[16]; int ci[16];
    const float* cv = cand_val + (size_t)row * (NKB * KSEL);
    const int*   cx = cand_idx + (size_t)row * (NKB * KSEL);
#pragma unroll
    for (int m = 0; m < 16; ++m) { const int p = lane + 64 * m; v[m] = cv[p]; ci[m] = cx[p]; }
    int wi_idx = 0;
#pragma unroll 1
    for (int it = 0; it < KSEL; ++it) {
        float bv = v[0]; int bj = 0;
#pragma unroll
        for (int m = 1; m < 16; ++m)
            if (v[m] > bv || (v[m] == bv && ci[m] < ci[bj])) { bv = v[m]; bj = m; }
        float rv = bv; int ridx = ci[bj];
#pragma unroll
        for (int off = 32; off >= 1; off >>= 1) {
            float ov = __shfl_xor(rv, off);
            int   oi = __shfl_xor(ridx, off);
            if (ov > rv || (ov == rv && oi < ridx)) { rv = ov; ridx = oi; }
        }
        if (lane == it) wi_idx = ridx;
        if (ci[bj] == ridx) v[bj] = -__builtin_inff();
    }
    if (lane < KSEL) topk[(size_t)row * KSEL + lane] = wi_idx;
}

// ---------------- Kernel C/E: out[row][col] = X[row][:] . W[col][:] + bias[col] ----------------
__global__ __launch_bounds__(256)
void gemm_bias_kernel(const float* __restrict__ X, const float* __restrict__ W,
                      const float* __restrict__ bias, void* __restrict__ outp,
                      const int store_bf16)
{
    __shared__ float Xs[BM][LDK];
    __shared__ float Ws[BN][LDK];
    const int tid  = threadIdx.x;
    const int lane = tid & 63;
    const int tr   = tid >> 6;
    const int row0 = blockIdx.x * BM;
    const int col0 = blockIdx.y * BN;

    float acc[8][8];
#pragma unroll
    for (int i = 0; i < 8; ++i)
#pragma unroll
        for (int j = 0; j < 8; ++j) acc[i][j] = 0.f;

    const int c4 = (tid & 3) * 4;
    const int rk = tid >> 2;
    const float* Wb = W + (size_t)col0 * DDIM;
    const float* Xb = X + (size_t)row0 * DDIM;

    for (int k0 = 0; k0 < DDIM; k0 += BK) {
        float4 wreg[8];
#pragma unroll
        for (int m = 0; m < 8; ++m)
            wreg[m] = *(const float4*)(Wb + (size_t)(rk + 64 * m) * DDIM + k0 + c4);
        float4 xreg;
        if (tid < 128)
            xreg = *(const float4*)(Xb + (size_t)rk * DDIM + k0 + c4);
        __syncthreads();
#pragma unroll
        for (int m = 0; m < 8; ++m)
            *(float4*)&Ws[rk + 64 * m][c4] = wreg[m];
        if (tid < 128)
            *(float4*)&Xs[rk][c4] = xreg;
        __syncthreads();
#pragma unroll
        for (int kc = 0; kc < BK; kc += 4) {
            float4 xf[8];
#pragma unroll
            for (int i = 0; i < 8; ++i) xf[i] = *(const float4*)&Xs[tr + 4 * i][kc];
#pragma unroll
            for (int j = 0; j < 8; ++j) {
                float4 wf = *(const float4*)&Ws[lane + 64 * j][kc];
#pragma unroll
                for (int i = 0; i < 8; ++i)
                    acc[i][j] += xf[i].x * wf.x + xf[i].y * wf.y + xf[i].z * wf.z + xf[i].w * wf.w;
            }
        }
    }

#pragma unroll
    for (int j = 0; j < 8; ++j) {
        const int col = col0 + lane + 64 * j;
        const float bz = bias[col];
#pragma unroll
        for (int i = 0; i < 8; ++i) {
            const int row = row0 + tr + 4 * i;
            const float val = acc[i][j] + bz;
            if (store_bf16)
                ((__hip_bfloat16*)outp)[(size_t)row * DDIM + col] = __float2bfloat16(val);
            else
                ((float*)outp)[(size_t)row * DDIM + col] = val;
        }
    }
}

// ---------------- Kernel D: per-token 8-head attention over 16 retrieved slots ----------------
// block = token, 4 waves, 2 heads/wave. lanes: jj=lane>>2 (slot 0..15), p=lane&3 (32-dim strip).
__global__ __launch_bounds__(256)
void attn_kernel(const float* __restrict__ Qp, const __hip_bfloat16* __restrict__ Kp,
                 const __hip_bfloat16* __restrict__ Vp, const int* __restrict__ topk,
                 float* __restrict__ attn_out)
{
    const int t = blockIdx.x;
    __shared__ int   idx_s[KSEL];
    __shared__ float sc_s[4][KSEL];
    if (threadIdx.x < KSEL) idx_s[threadIdx.x] = topk[(size_t)t * KSEL + threadIdx.x];
    __syncthreads();
    const int wv   = threadIdx.x >> 6;
    const int lane = threadIdx.x & 63;
    const int jj = lane >> 2, p = lane & 3;
    const float scale = 0.08838834764831845f;  // 1/sqrt(128)
    const unsigned short* Kpu = (const unsigned short*)Kp;
    const unsigned short* Vpu = (const unsigned short*)Vp;

#pragma unroll 1
    for (int hh = 0; hh < 2; ++hh) {
        const int h = wv * 2 + hh;
        const float* qh = Qp + (size_t)t * DDIM + h * HDIM + p * 32;
        const unsigned short* krow = Kpu + (size_t)idx_s[jj] * DDIM + h * HDIM + p * 32;
        float s = 0.f;
#pragma unroll
        for (int u = 0; u < 32; u += 8) {
            uint4  kv = *(const uint4*)(krow + u);
            float4 qa = *(const float4*)(qh + u);
            float4 qb = *(const float4*)(qh + u + 4);
            const unsigned short* kk = (const unsigned short*)&kv;
            s += bf2f(kk[0]) * qa.x + bf2f(kk[1]) * qa.y + bf2f(kk[2]) * qa.z + bf2f(kk[3]) * qa.w
               + bf2f(kk[4]) * qb.x + bf2f(kk[5]) * qb.y + bf2f(kk[6]) * qb.z + bf2f(kk[7]) * qb.w;
        }
        s += __shfl_xor(s, 1);
        s += __shfl_xor(s, 2);
        if (p == 0) sc_s[wv][jj] = s * scale;
        __syncthreads();
        float mx = -__builtin_inff();
#pragma unroll
        for (int n = 0; n < KSEL; ++n) mx = fmaxf(mx, sc_s[wv][n]);
        float wj[KSEL]; float wsum = 0.f;
#pragma unroll
        for (int n = 0; n < KSEL; ++n) { wj[n] = __expf(sc_s[wv][n] - mx); wsum += wj[n]; }
        const float inv = 1.f / wsum;
        const int d = lane * 2;
        float o0 = 0.f, o1 = 0.f;
#pragma unroll
        for (int n = 0; n < KSEL; ++n) {
            const unsigned int vv = *(const unsigned int*)(Vpu + (size_t)idx_s[n] * DDIM + h * HDIM + d);
            const float w = wj[n] * inv;
            o0 += w * bf2f((unsigned short)(vv & 0xffffu));
            o1 += w * bf2f((unsigned short)(vv >> 16));
        }
        *(float2*)(attn_out + (size_t)t * DDIM + h * HDIM + d) = make_float2(o0, o1);
        __syncthreads();   // protect sc_s before next head iteration
    }
}

extern "C" void kernel_launch(void* const* d_in, const int* in_sizes, int n_in,
                              void* d_out, int out_size, void* d_ws, size_t ws_size,
                              hipStream_t stream)
{
    const float* queries = (const float*)d_in[0];
    const float* mkeys   = (const float*)d_in[1];
    const float* mvals   = (const float*)d_in[2];
    const float* ipw     = (const float*)d_in[3];
    const float* ipb     = (const float*)d_in[4];
    const float* opw     = (const float*)d_in[5];
    const float* opb     = (const float*)d_in[6];
    // d_in[7] = k (always 16; layouts hardcoded)

    char* ws = (char*)d_ws;
    size_t off = 0;
    auto alloc = [&](size_t bytes) -> char* {
        char* p = ws + off;
        off += (bytes + 255) & ~(size_t)255;
        return p;
    };
    float* cand_val = (float*)alloc((size_t)NROWS * NKB * KSEL * 4);   // 16.8 MB
    int*   cand_idx = (int*)  alloc((size_t)NROWS * NKB * KSEL * 4);   // 16.8 MB
    int*   topk     = (int*)  alloc((size_t)NROWS * KSEL * 4);         // 0.26 MB
    float* Qp       = (float*)alloc((size_t)NROWS * DDIM * 4);         // 16.8 MB
    __hip_bfloat16* Kp = (__hip_bfloat16*)alloc((size_t)MKEYS * DDIM * 2);  // 67 MB
    __hip_bfloat16* Vp = (__hip_bfloat16*)alloc((size_t)MKEYS * DDIM * 2);  // 67 MB
    float* attn_out = (float*)alloc((size_t)NROWS * DDIM * 4);         // 16.8 MB  (total ~202 MB)

    // 1) similarity GEMM + per-keyblock top-16
    sims_topk_kernel<<<dim3(NROWS / BM, MKEYS / BN), 256, 0, stream>>>(queries, mkeys, cand_val, cand_idx);
    // 2) merge to global top-16 indices
    topk_merge_kernel<<<NROWS / 4, 256, 0, stream>>>(cand_val, cand_idx, topk);
    // 3) projections: q (f32), and the WHOLE memory bank through Wk/Wv (bf16 storage)
    gemm_bias_kernel<<<dim3(NROWS / BM, DDIM / BN), 256, 0, stream>>>(queries, ipw, ipb, Qp, 0);
    gemm_bias_kernel<<<dim3(MKEYS / BM, DDIM / BN), 256, 0, stream>>>(mkeys, ipw + (size_t)DDIM * DDIM, ipb + DDIM, Kp, 1);
    gemm_bias_kernel<<<dim3(MKEYS / BM, DDIM / BN), 256, 0, stream>>>(mvals, ipw + 2 * (size_t)DDIM * DDIM, ipb + 2 * DDIM, Vp, 1);
    // 4) gather + attention
    attn_kernel<<<NROWS, 256, 0, stream>>>(Qp, Kp, Vp, topk, attn_out);
    // 5) output projection -> d_out (f32)
    gemm_bias_kernel<<<dim3(NROWS / BM, DDIM / BN), 256, 0, stream>>>(attn_out, opw, opb, d_out, 0);
}

// Round 2
// 11386.037 us; speedup vs baseline: 1.8534x; 1.8534x over previous
//
#include <hip/hip_runtime.h>
#include <hip/hip_bf16.h>

#define NROWS 4096    // B*S
#define DDIM  1024
#define MKEYS 32768
#define HDIM  128
#define KSEL  16

// ---- sims MFMA GEMM geometry ----
#define SBM 128            // rows per block
#define SBN 256            // keys per block
#define SNKB (MKEYS / SBN) // 128 key blocks
#define CANDS_PER_ROW (SNKB * KSEL)   // 2048

// ---- old fp32 gemm_bias geometry (unchanged, known-good) ----
constexpr int BM = 32, BN = 512, BK = 16, LDK = 20;

typedef short bf16x8 __attribute__((ext_vector_type(8)));
typedef float f32x4  __attribute__((ext_vector_type(4)));

__device__ __forceinline__ float bf2f(unsigned short u) {
    union { unsigned int i; float f; } x; x.i = ((unsigned int)u) << 16; return x.f;
}
__device__ __forceinline__ unsigned short f2bf(float f) {
    union { float f; unsigned int u; } v; v.f = f;
    unsigned int r = (v.u + 0x7fffu + ((v.u >> 16) & 1u)) >> 16;   // RNE
    return (unsigned short)r;
}
__device__ __forceinline__ void gload16(const void* g, const void* l) {
    __builtin_amdgcn_global_load_lds((const __attribute__((address_space(1))) unsigned int*)g,
                                     (__attribute__((address_space(3))) unsigned int*)l, 16, 0, 0);
}
// sorted-descending top-16 insertion, fully static indexing (no scratch)
__device__ __forceinline__ void ins16(float v, int id, float* lv, int* li) {
    if (v > lv[15]) {
#pragma unroll
        for (int i = 0; i < 16; ++i) {
            const bool gt = v > lv[i];
            const float tv = gt ? lv[i] : v;
            const int   ti = gt ? li[i] : id;
            if (gt) { lv[i] = v; li[i] = id; }
            v = tv; id = ti;
        }
    }
}

// ---------------- Kernel 0: fp32 -> (hi, lo) bf16 split ----------------
__global__ __launch_bounds__(256)
void split_bf16_kernel(const float* __restrict__ x, unsigned short* __restrict__ hi,
                       unsigned short* __restrict__ lo, const int n4)
{
    int i = blockIdx.x * 256 + threadIdx.x;
    const int stride = gridDim.x * 256;
    for (; i < n4; i += stride) {
        const float4 f = ((const float4*)x)[i];
        ushort4 h, l;
        h.x = f2bf(f.x); l.x = f2bf(f.x - bf2f(h.x));
        h.y = f2bf(f.y); l.y = f2bf(f.y - bf2f(h.y));
        h.z = f2bf(f.z); l.z = f2bf(f.z - bf2f(h.z));
        h.w = f2bf(f.w); l.w = f2bf(f.w - bf2f(h.w));
        ((ushort4*)hi)[i] = h;
        ((ushort4*)lo)[i] = l;
    }
}

// ---------------- Kernel A: sims = Q.K^T via split-bf16 MFMA, fused per-keyblock top-16 ----------------
// 128x256 tile, BK=64, logical K = 3 segments x 1024: (Qhi,Khi),(Qlo,Khi),(Qhi,Klo).
// 4 waves as 2x2; wave tile 64x128 (acc 4x8 frags of 16x16).
// LDS: A tile [128][64]bf16 @0 (16KB), B tile [256][64]bf16 @16KB (32KB); epilogue C [128][68]f32 unions.
// Swizzle: byte_col ^= ((row&7)<<4), applied on global SOURCE at stage + on ds_read (rule #21).
__global__ __launch_bounds__(256)
void sims_mfma_kernel(const unsigned short* __restrict__ Qhi, const unsigned short* __restrict__ Qlo,
                      const unsigned short* __restrict__ Khi, const unsigned short* __restrict__ Klo,
                      float* __restrict__ cand_val, int* __restrict__ cand_idx)
{
    __shared__ char smem[49152];
    const int tid  = threadIdx.x;
    const int lane = tid & 63;
    const int w    = tid >> 6;
    const int wr   = w >> 1, wc = w & 1;
    const int row0 = blockIdx.x * SBM;
    const int key0 = blockIdx.y * SBN;

    const f32x4 zero = {0.f, 0.f, 0.f, 0.f};
    f32x4 acc[4][8];
#pragma unroll
    for (int mi = 0; mi < 4; ++mi)
#pragma unroll
        for (int ni = 0; ni < 8; ++ni) acc[mi][ni] = zero;

    // staging address helpers: chunk = 1KB = 8 rows x 128B; lane covers (row = chunk*8 + lane>>3, 16B slot)
    const int srow = lane >> 3;                                   // row within chunk, == row&7
    const int scol = (((lane & 7) ^ srow) << 4);                  // pre-swizzled source byte col [0,128)

    for (int step = 0; step < 48; ++step) {
        const int seg   = step >> 4;
        const int kbyte = (step & 15) << 7;                       // 64 bf16 = 128B per step
        const unsigned short* Ab = (seg == 1) ? Qlo : Qhi;
        const unsigned short* Bb = (seg == 2) ? Klo : Khi;
        __syncthreads();                                          // prev step's ds_reads done
#pragma unroll
        for (int i = 0; i < 12; ++i) {
            const int chunk = w + (i << 2);                       // wave-uniform
            const char* src;
            if (chunk < 16) {                                     // A: rows 0..127
                const int r = (chunk << 3) + srow;
                src = (const char*)Ab + (((size_t)(row0 + r)) << 11) + kbyte + scol;
            } else {                                              // B: keys 0..255
                const int r = ((chunk - 16) << 3) + srow;
                src = (const char*)Bb + (((size_t)(key0 + r)) << 11) + kbyte + scol;
            }
            gload16(src, smem + (chunk << 10));
        }
        asm volatile("s_waitcnt vmcnt(0)" ::: "memory");
        __syncthreads();
#pragma unroll
        for (int kk = 0; kk < 2; ++kk) {
            const int cb = (kk << 6) + ((lane >> 4) << 4);
            bf16x8 af[4], bf[8];
#pragma unroll
            for (int mi = 0; mi < 4; ++mi) {
                const int r = wr * 64 + mi * 16 + (lane & 15);
                af[mi] = *(const bf16x8*)(smem + r * 128 + (cb ^ ((r & 7) << 4)));
            }
#pragma unroll
            for (int ni = 0; ni < 8; ++ni) {
                const int r = wc * 128 + ni * 16 + (lane & 15);
                bf[ni] = *(const bf16x8*)(smem + 16384 + r * 128 + (cb ^ ((r & 7) << 4)));
            }
#pragma unroll
            for (int mi = 0; mi < 4; ++mi)
#pragma unroll
                for (int ni = 0; ni < 8; ++ni)
                    acc[mi][ni] = __builtin_amdgcn_mfma_f32_16x16x32_bf16(af[mi], bf[ni], acc[mi][ni], 0, 0, 0);
        }
    }

    // ---- fused top-16 epilogue: 4 quarter-passes of 64 cols through LDS C tile ----
    float lv[16]; int li[16];
#pragma unroll
    for (int i = 0; i < 16; ++i) { lv[i] = -3.4e38f; li[i] = 0; }
    float* C_lds = (float*)smem;                                  // [128][68] f32 (pad 4 -> 2-way-free)

#pragma unroll 1
    for (int q = 0; q < 4; ++q) {
        __syncthreads();
        if (wc == (q >> 1)) {                                     // waves owning these 64 block-cols
#pragma unroll
            for (int mi = 0; mi < 4; ++mi)
#pragma unroll
                for (int nn = 0; nn < 4; ++nn) {
                    const int ni = ((q & 1) << 2) + nn;
                    const int r  = wr * 64 + mi * 16 + ((lane >> 4) << 2);
                    const int c  = nn * 16 + (lane & 15);
                    const f32x4 v = acc[mi][ni];
#pragma unroll
                    for (int j = 0; j < 4; ++j) C_lds[(r + j) * 68 + c] = v[j];
                }
        }
        __syncthreads();
        if (tid < 128) {                                          // thread t scans row t
            const int gbase = key0 + (q << 6);
#pragma unroll 1
            for (int c4 = 0; c4 < 16; ++c4) {
                const float4 vv = *(const float4*)&C_lds[tid * 68 + (c4 << 2)];
                const float thr = lv[15];
                if (vv.x > thr || vv.y > thr || vv.z > thr || vv.w > thr) {
                    ins16(vv.x, gbase + c4 * 4 + 0, lv, li);
                    ins16(vv.y, gbase + c4 * 4 + 1, lv, li);
                    ins16(vv.z, gbase + c4 * 4 + 2, lv, li);
                    ins16(vv.w, gbase + c4 * 4 + 3, lv, li);
                }
            }
        }
    }
    if (tid < 128) {
        const size_t o = (((size_t)(row0 + tid)) * SNKB + blockIdx.y) * KSEL;
#pragma unroll
        for (int i = 0; i < 16; ++i) { cand_val[o + i] = lv[i]; cand_idx[o + i] = li[i]; }
    }
}

// ---------------- Kernel B: merge 128 blocks x 16 candidates -> global top-16 per row ----------------
__global__ __launch_bounds__(256)
void topk_merge_kernel(const float* __restrict__ cand_val, const int* __restrict__ cand_idx,
                       int* __restrict__ topk)
{
    const int row  = blockIdx.x * 4 + (threadIdx.x >> 6);
    const int lane = threadIdx.x & 63;
    const size_t base = (size_t)row * CANDS_PER_ROW;
    float lv[16]; int li[16];
#pragma unroll
    for (int i = 0; i < 16; ++i) { lv[i] = -3.4e38f; li[i] = 0x7fffffff; }
#pragma unroll 1
    for (int m = 0; m < CANDS_PER_ROW / 64; ++m) {                // 32 per lane
        const int p = lane + (m << 6);
        ins16(cand_val[base + p], cand_idx[base + p], lv, li);
    }
    int out = 0;
#pragma unroll 1
    for (int it = 0; it < KSEL; ++it) {
        float rv = lv[0]; int ridx = li[0];
#pragma unroll
        for (int off = 1; off < 64; off <<= 1) {
            const float ov = __shfl_xor(rv, off);
            const int   oi = __shfl_xor(ridx, off);
            if (ov > rv || (ov == rv && oi < ridx)) { rv = ov; ridx = oi; }
        }
        if (lane == it) out = ridx;
        if (li[0] == ridx) {                                      // winner lane pops head (static shift)
#pragma unroll
            for (int i = 0; i < 15; ++i) { lv[i] = lv[i + 1]; li[i] = li[i + 1]; }
            lv[15] = -3.4e38f; li[15] = 0x7fffffff;
        }
    }
    if (lane < KSEL) topk[(size_t)row * KSEL + lane] = out;
}

// ---------------- Kernel C/E: out[row][col] = X[row][:] . W[col][:] + bias[col] (fp32, unchanged) ----------------
__global__ __launch_bounds__(256)
void gemm_bias_kernel(const float* __restrict__ X, const float* __restrict__ W,
                      const float* __restrict__ bias, void* __restrict__ outp,
                      const int store_bf16)
{
    __shared__ float Xs[BM][LDK];
    __shared__ float Ws[BN][LDK];
    const int tid  = threadIdx.x;
    const int lane = tid & 63;
    const int tr   = tid >> 6;
    const int row0 = blockIdx.x * BM;
    const int col0 = blockIdx.y * BN;

    float acc[8][8];
#pragma unroll
    for (int i = 0; i < 8; ++i)
#pragma unroll
        for (int j = 0; j < 8; ++j) acc[i][j] = 0.f;

    const int c4 = (tid & 3) * 4;
    const int rk = tid >> 2;
    const float* Wb = W + (size_t)col0 * DDIM;
    const float* Xb = X + (size_t)row0 * DDIM;

    for (int k0 = 0; k0 < DDIM; k0 += BK) {
        float4 wreg[8];
#pragma unroll
        for (int m = 0; m < 8; ++m)
            wreg[m] = *(const float4*)(Wb + (size_t)(rk + 64 * m) * DDIM + k0 + c4);
        float4 xreg;
        if (tid < 128)
            xreg = *(const float4*)(Xb + (size_t)rk * DDIM + k0 + c4);
        __syncthreads();
#pragma unroll
        for (int m = 0; m < 8; ++m)
            *(float4*)&Ws[rk + 64 * m][c4] = wreg[m];
        if (tid < 128)
            *(float4*)&Xs[rk][c4] = xreg;
        __syncthreads();
#pragma unroll
        for (int kc = 0; kc < BK; kc += 4) {
            float4 xf[8];
#pragma unroll
            for (int i = 0; i < 8; ++i) xf[i] = *(const float4*)&Xs[tr + 4 * i][kc];
#pragma unroll
            for (int j = 0; j < 8; ++j) {
                float4 wf = *(const float4*)&Ws[lane + 64 * j][kc];
#pragma unroll
                for (int i = 0; i < 8; ++i)
                    acc[i][j] += xf[i].x * wf.x + xf[i].y * wf.y + xf[i].z * wf.z + xf[i].w * wf.w;
            }
        }
    }

#pragma unroll
    for (int j = 0; j < 8; ++j) {
        const int col = col0 + lane + 64 * j;
        const float bz = bias[col];
#pragma unroll
        for (int i = 0; i < 8; ++i) {
            const int row = row0 + tr + 4 * i;
            const float val = acc[i][j] + bz;
            if (store_bf16)
                ((__hip_bfloat16*)outp)[(size_t)row * DDIM + col] = __float2bfloat16(val);
            else
                ((float*)outp)[(size_t)row * DDIM + col] = val;
        }
    }
}

// ---------------- Kernel D: per-token 8-head attention over 16 retrieved slots (unchanged) ----------------
__global__ __launch_bounds__(256)
void attn_kernel(const float* __restrict__ Qp, const __hip_bfloat16* __restrict__ Kp,
                 const __hip_bfloat16* __restrict__ Vp, const int* __restrict__ topk,
                 float* __restrict__ attn_out)
{
    const int t = blockIdx.x;
    __shared__ int   idx_s[KSEL];
    __shared__ float sc_s[4][KSEL];
    if (threadIdx.x < KSEL) idx_s[threadIdx.x] = topk[(size_t)t * KSEL + threadIdx.x];
    __syncthreads();
    const int wv   = threadIdx.x >> 6;
    const int lane = threadIdx.x & 63;
    const int jj = lane >> 2, p = lane & 3;
    const float scale = 0.08838834764831845f;  // 1/sqrt(128)
    const unsigned short* Kpu = (const unsigned short*)Kp;
    const unsigned short* Vpu = (const unsigned short*)Vp;

#pragma unroll 1
    for (int hh = 0; hh < 2; ++hh) {
        const int h = wv * 2 + hh;
        const float* qh = Qp + (size_t)t * DDIM + h * HDIM + p * 32;
        const unsigned short* krow = Kpu + (size_t)idx_s[jj] * DDIM + h * HDIM + p * 32;
        float s = 0.f;
#pragma unroll
        for (int u = 0; u < 32; u += 8) {
            uint4  kv = *(const uint4*)(krow + u);
            float4 qa = *(const float4*)(qh + u);
            float4 qb = *(const float4*)(qh + u + 4);
            const unsigned short* kk = (const unsigned short*)&kv;
            s += bf2f(kk[0]) * qa.x + bf2f(kk[1]) * qa.y + bf2f(kk[2]) * qa.z + bf2f(kk[3]) * qa.w
               + bf2f(kk[4]) * qb.x + bf2f(kk[5]) * qb.y + bf2f(kk[6]) * qb.z + bf2f(kk[7]) * qb.w;
        }
        s += __shfl_xor(s, 1);
        s += __shfl_xor(s, 2);
        if (p == 0) sc_s[wv][jj] = s * scale;
        __syncthreads();
        float mx = -__builtin_inff();
#pragma unroll
        for (int n = 0; n < KSEL; ++n) mx = fmaxf(mx, sc_s[wv][n]);
        float wj[KSEL]; float wsum = 0.f;
#pragma unroll
        for (int n = 0; n < KSEL; ++n) { wj[n] = __expf(sc_s[wv][n] - mx); wsum += wj[n]; }
        const float inv = 1.f / wsum;
        const int d = lane * 2;
        float o0 = 0.f, o1 = 0.f;
#pragma unroll
        for (int n = 0; n < KSEL; ++n) {
            const unsigned int vv = *(const unsigned int*)(Vpu + (size_t)idx_s[n] * DDIM + h * HDIM + d);
            const float w = wj[n] * inv;
            o0 += w * bf2f((unsigned short)(vv & 0xffffu));
            o1 += w * bf2f((unsigned short)(vv >> 16));
        }
        *(float2*)(attn_out + (size_t)t * DDIM + h * HDIM + d) = make_float2(o0, o1);
        __syncthreads();
    }
}

extern "C" void kernel_launch(void* const* d_in, const int* in_sizes, int n_in,
                              void* d_out, int out_size, void* d_ws, size_t ws_size,
                              hipStream_t stream)
{
    const float* queries = (const float*)d_in[0];
    const float* mkeys   = (const float*)d_in[1];
    const float* mvals   = (const float*)d_in[2];
    const float* ipw     = (const float*)d_in[3];
    const float* ipb     = (const float*)d_in[4];
    const float* opw     = (const float*)d_in[5];
    const float* opb     = (const float*)d_in[6];

    char* ws = (char*)d_ws;
    size_t off = 0;
    auto alloc = [&](size_t bytes) -> char* {
        char* p = ws + off;
        off += (bytes + 255) & ~(size_t)255;
        return p;
    };
    unsigned short* Khi = (unsigned short*)alloc((size_t)MKEYS * DDIM * 2);   // 67.1 MB
    unsigned short* Klo = (unsigned short*)alloc((size_t)MKEYS * DDIM * 2);   // 67.1 MB
    unsigned short* Qhi = (unsigned short*)alloc((size_t)NROWS * DDIM * 2);   // 8.4 MB
    unsigned short* Qlo = (unsigned short*)alloc((size_t)NROWS * DDIM * 2);   // 8.4 MB
    float* cand_val = (float*)alloc((size_t)NROWS * CANDS_PER_ROW * 4);       // 33.5 MB
    int*   cand_idx = (int*)  alloc((size_t)NROWS * CANDS_PER_ROW * 4);       // 33.5 MB
    int*   topk     = (int*)  alloc((size_t)NROWS * KSEL * 4);                // 0.26 MB
    // aliases (stream-ordered reuse): total ws ~218 MB
    float* Qp       = (float*)cand_val;            // written after merge
    float* attn_out = (float*)cand_idx;            // written by attn
    __hip_bfloat16* Kp = (__hip_bfloat16*)Khi;     // written by proj after sims
    __hip_bfloat16* Vp = (__hip_bfloat16*)Klo;

    // 0) split fp32 -> hi/lo bf16
    split_bf16_kernel<<<2048, 256, 0, stream>>>(queries, Qhi, Qlo, NROWS * DDIM / 4);
    split_bf16_kernel<<<2048, 256, 0, stream>>>(mkeys, Khi, Klo, MKEYS * DDIM / 4);
    // 1) similarity GEMM (split-bf16 MFMA) + per-keyblock top-16
    sims_mfma_kernel<<<dim3(NROWS / SBM, MKEYS / SBN), 256, 0, stream>>>(Qhi, Qlo, Khi, Klo, cand_val, cand_idx);
    // 2) merge to global top-16 indices
    topk_merge_kernel<<<NROWS / 4, 256, 0, stream>>>(cand_val, cand_idx, topk);
    // 3) projections: q (f32), whole memory bank through Wk/Wv (bf16 storage)
    gemm_bias_kernel<<<dim3(NROWS / BM, DDIM / BN), 256, 0, stream>>>(queries, ipw, ipb, Qp, 0);
    gemm_bias_kernel<<<dim3(MKEYS / BM, DDIM / BN), 256, 0, stream>>>(mkeys, ipw + (size_t)DDIM * DDIM, ipb + DDIM, Kp, 1);
    gemm_bias_kernel<<<dim3(MKEYS / BM, DDIM / BN), 256, 0, stream>>>(mvals, ipw + 2 * (size_t)DDIM * DDIM, ipb + 2 * DDIM, Vp, 1);
    // 4) gather + attention
    attn_kernel<<<NROWS, 256, 0, stream>>>(Qp, Kp, Vp, topk, attn_out);
    // 5) output projection -> d_out (f32)
    gemm_bias_kernel<<<dim3(NROWS / BM, DDIM / BN), 256, 0, stream>>>(attn_out, opw, opb, d_out, 0);
}

// Round 3
// 3386.052 us; speedup vs baseline: 6.2323x; 3.3626x over previous
//
#include <hip/hip_runtime.h>
#include <hip/hip_bf16.h>

#define NROWS 4096    // B*S
#define DDIM  1024
#define MKEYS 32768
#define HDIM  128
#define KSEL  16

// ---- sims MFMA GEMM geometry ----
#define SBM 128            // rows per block
#define SBN 256            // keys per block
#define SNKB (MKEYS / SBN) // 128 key blocks
#define CANDS_PER_ROW (SNKB * KSEL)   // 2048

typedef short bf16x8 __attribute__((ext_vector_type(8)));
typedef float f32x4  __attribute__((ext_vector_type(4)));

__device__ __forceinline__ float bf2f(unsigned short u) {
    union { unsigned int i; float f; } x; x.i = ((unsigned int)u) << 16; return x.f;
}
__device__ __forceinline__ unsigned short f2bf(float f) {
    union { float f; unsigned int u; } v; v.f = f;
    unsigned int r = (v.u + 0x7fffu + ((v.u >> 16) & 1u)) >> 16;   // RNE
    return (unsigned short)r;
}
__device__ __forceinline__ void gload16(const void* g, const void* l) {
    __builtin_amdgcn_global_load_lds((const __attribute__((address_space(1))) unsigned int*)g,
                                     (__attribute__((address_space(3))) unsigned int*)l, 16, 0, 0);
}
// sorted-descending top-16 insertion, fully static indexing (no scratch)
__device__ __forceinline__ void ins16(float v, int id, float* lv, int* li) {
    if (v > lv[15]) {
#pragma unroll
        for (int i = 0; i < 16; ++i) {
            const bool gt = v > lv[i];
            const float tv = gt ? lv[i] : v;
            const int   ti = gt ? li[i] : id;
            if (gt) { lv[i] = v; li[i] = id; }
            v = tv; id = ti;
        }
    }
}
// trunc-hi / RNE-lo split of two fp32 -> packed bf16 pair words
__device__ __forceinline__ void split2(float x0, float x1, unsigned int& hp, unsigned int& lp) {
    union { float f; unsigned int u; } u0, u1;
    u0.f = x0; u1.f = x1;
    hp = (u0.u >> 16) | (u1.u & 0xffff0000u);
    const float r0 = x0 - bf2f((unsigned short)(u0.u >> 16));
    const float r1 = x1 - bf2f((unsigned short)(u1.u >> 16));
    lp = (unsigned int)f2bf(r0) | ((unsigned int)f2bf(r1) << 16);
}

// ---------------- Kernel 0: fp32 -> (hi, lo) bf16 split ----------------
__global__ __launch_bounds__(256)
void split_bf16_kernel(const float* __restrict__ x, unsigned short* __restrict__ hi,
                       unsigned short* __restrict__ lo, const int n4)
{
    int i = blockIdx.x * 256 + threadIdx.x;
    const int stride = gridDim.x * 256;
    for (; i < n4; i += stride) {
        const float4 f = ((const float4*)x)[i];
        ushort4 h, l;
        h.x = f2bf(f.x); l.x = f2bf(f.x - bf2f(h.x));
        h.y = f2bf(f.y); l.y = f2bf(f.y - bf2f(h.y));
        h.z = f2bf(f.z); l.z = f2bf(f.z - bf2f(h.z));
        h.w = f2bf(f.w); l.w = f2bf(f.w - bf2f(h.w));
        ((ushort4*)hi)[i] = h;
        ((ushort4*)lo)[i] = l;
    }
}

// ---------------- Kernel A: sims = Q.K^T via split-bf16 MFMA, fused per-keyblock top-16 ----------------
__global__ __launch_bounds__(256)
void sims_mfma_kernel(const unsigned short* __restrict__ Qhi, const unsigned short* __restrict__ Qlo,
                      const unsigned short* __restrict__ Khi, const unsigned short* __restrict__ Klo,
                      float* __restrict__ cand_val, int* __restrict__ cand_idx)
{
    __shared__ char smem[49152];
    const int tid  = threadIdx.x;
    const int lane = tid & 63;
    const int w    = tid >> 6;
    const int wr   = w >> 1, wc = w & 1;
    const int row0 = blockIdx.x * SBM;
    const int key0 = blockIdx.y * SBN;

    const f32x4 zero = {0.f, 0.f, 0.f, 0.f};
    f32x4 acc[4][8];
#pragma unroll
    for (int mi = 0; mi < 4; ++mi)
#pragma unroll
        for (int ni = 0; ni < 8; ++ni) acc[mi][ni] = zero;

    const int srow = lane >> 3;                                   // row within chunk, == row&7
    const int scol = (((lane & 7) ^ srow) << 4);                  // pre-swizzled source byte col [0,128)

    for (int step = 0; step < 48; ++step) {
        const int seg   = step >> 4;
        const int kbyte = (step & 15) << 7;                       // 64 bf16 = 128B per step
        const unsigned short* Ab = (seg == 1) ? Qlo : Qhi;
        const unsigned short* Bb = (seg == 2) ? Klo : Khi;
        __syncthreads();                                          // prev step's ds_reads done
#pragma unroll
        for (int i = 0; i < 12; ++i) {
            const int chunk = w + (i << 2);                       // wave-uniform
            const char* src;
            if (chunk < 16) {                                     // A: rows 0..127
                const int r = (chunk << 3) + srow;
                src = (const char*)Ab + (((size_t)(row0 + r)) << 11) + kbyte + scol;
            } else {                                              // B: keys 0..255
                const int r = ((chunk - 16) << 3) + srow;
                src = (const char*)Bb + (((size_t)(key0 + r)) << 11) + kbyte + scol;
            }
            gload16(src, smem + (chunk << 10));
        }
        asm volatile("s_waitcnt vmcnt(0)" ::: "memory");
        __syncthreads();
#pragma unroll
        for (int kk = 0; kk < 2; ++kk) {
            const int cb = (kk << 6) + ((lane >> 4) << 4);
            bf16x8 af[4], bf[8];
#pragma unroll
            for (int mi = 0; mi < 4; ++mi) {
                const int r = wr * 64 + mi * 16 + (lane & 15);
                af[mi] = *(const bf16x8*)(smem + r * 128 + (cb ^ ((r & 7) << 4)));
            }
#pragma unroll
            for (int ni = 0; ni < 8; ++ni) {
                const int r = wc * 128 + ni * 16 + (lane & 15);
                bf[ni] = *(const bf16x8*)(smem + 16384 + r * 128 + (cb ^ ((r & 7) << 4)));
            }
#pragma unroll
            for (int mi = 0; mi < 4; ++mi)
#pragma unroll
                for (int ni = 0; ni < 8; ++ni)
                    acc[mi][ni] = __builtin_amdgcn_mfma_f32_16x16x32_bf16(af[mi], bf[ni], acc[mi][ni], 0, 0, 0);
        }
    }

    // ---- fused top-16 epilogue: FULLY UNROLLED q (static acc indices -> no scratch) ----
    float lv[16]; int li[16];
#pragma unroll
    for (int i = 0; i < 16; ++i) { lv[i] = -3.4e38f; li[i] = 0; }
    float* C_lds = (float*)smem;                                  // [128][68] f32

#pragma unroll
    for (int q = 0; q < 4; ++q) {
        __syncthreads();
        if (wc == (q >> 1)) {
#pragma unroll
            for (int mi = 0; mi < 4; ++mi)
#pragma unroll
                for (int nn = 0; nn < 4; ++nn) {
                    const int ni = ((q & 1) << 2) + nn;
                    const int r  = wr * 64 + mi * 16 + ((lane >> 4) << 2);
                    const int c  = nn * 16 + (lane & 15);
                    const f32x4 v = acc[mi][ni];
#pragma unroll
                    for (int j = 0; j < 4; ++j) C_lds[(r + j) * 68 + c] = v[j];
                }
        }
        __syncthreads();
        if (tid < 128) {
            const int gbase = key0 + (q << 6);
#pragma unroll 1
            for (int c4 = 0; c4 < 16; ++c4) {
                const float4 vv = *(const float4*)&C_lds[tid * 68 + (c4 << 2)];
                const float thr = lv[15];
                if (vv.x > thr || vv.y > thr || vv.z > thr || vv.w > thr) {
                    ins16(vv.x, gbase + c4 * 4 + 0, lv, li);
                    ins16(vv.y, gbase + c4 * 4 + 1, lv, li);
                    ins16(vv.z, gbase + c4 * 4 + 2, lv, li);
                    ins16(vv.w, gbase + c4 * 4 + 3, lv, li);
                }
            }
        }
    }
    if (tid < 128) {
        const size_t o = (((size_t)(row0 + tid)) * SNKB + blockIdx.y) * KSEL;
#pragma unroll
        for (int i = 0; i < 16; ++i) { cand_val[o + i] = lv[i]; cand_idx[o + i] = li[i]; }
    }
}

// ---------------- Kernel B: merge 128 blocks x 16 candidates -> global top-16 per row ----------------
__global__ __launch_bounds__(256)
void topk_merge_kernel(const float* __restrict__ cand_val, const int* __restrict__ cand_idx,
                       int* __restrict__ topk)
{
    const int row  = blockIdx.x * 4 + (threadIdx.x >> 6);
    const int lane = threadIdx.x & 63;
    const size_t base = (size_t)row * CANDS_PER_ROW;
    float lv[16]; int li[16];
#pragma unroll
    for (int i = 0; i < 16; ++i) { lv[i] = -3.4e38f; li[i] = 0x7fffffff; }
#pragma unroll 1
    for (int m = 0; m < CANDS_PER_ROW / 64; ++m) {                // 32 per lane
        const int p = lane + (m << 6);
        ins16(cand_val[base + p], cand_idx[base + p], lv, li);
    }
    int out = 0;
#pragma unroll 1
    for (int it = 0; it < KSEL; ++it) {
        float rv = lv[0]; int ridx = li[0];
#pragma unroll
        for (int off = 1; off < 64; off <<= 1) {
            const float ov = __shfl_xor(rv, off);
            const int   oi = __shfl_xor(ridx, off);
            if (ov > rv || (ov == rv && oi < ridx)) { rv = ov; ridx = oi; }
        }
        if (lane == it) out = ridx;
        if (li[0] == ridx) {
#pragma unroll
            for (int i = 0; i < 15; ++i) { lv[i] = lv[i + 1]; li[i] = li[i + 1]; }
            lv[15] = -3.4e38f; li[15] = 0x7fffffff;
        }
    }
    if (lane < KSEL) topk[(size_t)row * KSEL + lane] = out;
}

// ---------------- Kernel C: projections via split-bf16 MFMA ----------------
// out[row][col] = X[row,:].W[col,:] + bias[col]; X fp32 (inline hi/lo split, reg-staged),
// W pre-split bf16 hi/lo. 128x128 block tile, 4 waves 2x2 (wave tile 64x64), BK=64.
// LDS 64KB: Xhi@0(16K) Xlo@16K Whi@32K(16K) Wlo@48K. Swizzle byte^=((row&7)<<4) both sides.
__global__ __launch_bounds__(256)
void proj_split_kernel(const float* __restrict__ X, const unsigned short* __restrict__ Whi,
                       const unsigned short* __restrict__ Wlo, const float* __restrict__ bias,
                       void* __restrict__ outp, const int store_bf16)
{
    __shared__ char smem[65536];
    const int tid  = threadIdx.x;
    const int lane = tid & 63;
    const int w    = tid >> 6;
    const int wr   = w >> 1, wc = w & 1;
    const int row0 = blockIdx.x * 128;
    const int col0 = blockIdx.y * 128;

    const f32x4 zero = {0.f, 0.f, 0.f, 0.f};
    f32x4 acc[4][4];
#pragma unroll
    for (int mi = 0; mi < 4; ++mi)
#pragma unroll
        for (int ni = 0; ni < 4; ++ni) acc[mi][ni] = zero;

    const int srow = lane >> 3;
    const int scol = (((lane & 7) ^ srow) << 4);
    const int xr = tid >> 1, xh = tid & 1;                        // X staging: row, 32-col half

    for (int step = 0; step < 16; ++step) {
        const int kbyte = step << 7;                              // bf16 plane byte offset
        const int k0    = step << 6;                              // fp32 element offset
        __syncthreads();
        // stage W hi/lo planes: 32 chunks of 1KB (8 rows x 128B each)
#pragma unroll
        for (int i = 0; i < 8; ++i) {
            const int chunk = w + (i << 2);                       // 0..31
            const int plane = chunk >> 4;                         // 0 hi, 1 lo
            const int r     = ((chunk & 15) << 3) + srow;         // 0..127
            const unsigned short* Wb = plane ? Wlo : Whi;
            const char* src = (const char*)Wb + (((size_t)(col0 + r)) << 11) + kbyte + scol;
            gload16(src, smem + 32768 + (chunk << 10));
        }
        // stage X: load 32 fp32, split inline, swizzled ds_write_b128 per 16B slot
        {
            const float* Xp = X + (size_t)(row0 + xr) * DDIM + k0 + xh * 32;
            float4 xa[8];
#pragma unroll
            for (int i = 0; i < 8; ++i) xa[i] = ((const float4*)Xp)[i];
            const int xbase = xr * 128;
#pragma unroll
            for (int s4 = 0; s4 < 4; ++s4) {
                const float4 a = xa[2 * s4], b = xa[2 * s4 + 1];
                uint4 hw, lw;
                split2(a.x, a.y, hw.x, lw.x);
                split2(a.z, a.w, hw.y, lw.y);
                split2(b.x, b.y, hw.z, lw.z);
                split2(b.z, b.w, hw.w, lw.w);
                const int off = xbase + ((((xh << 2) + s4) ^ (xr & 7)) << 4);
                *(uint4*)(smem + off)         = hw;
                *(uint4*)(smem + 16384 + off) = lw;
            }
        }
        asm volatile("s_waitcnt vmcnt(0)" ::: "memory");
        __syncthreads();
#pragma unroll
        for (int kk = 0; kk < 2; ++kk) {
            const int cb = (kk << 6) + ((lane >> 4) << 4);
            bf16x8 ah[4], bh[4];
#pragma unroll
            for (int mi = 0; mi < 4; ++mi) {
                const int r = wr * 64 + mi * 16 + (lane & 15);
                ah[mi] = *(const bf16x8*)(smem + r * 128 + (cb ^ ((r & 7) << 4)));
            }
#pragma unroll
            for (int ni = 0; ni < 4; ++ni) {
                const int r = wc * 64 + ni * 16 + (lane & 15);
                bh[ni] = *(const bf16x8*)(smem + 32768 + r * 128 + (cb ^ ((r & 7) << 4)));
            }
#pragma unroll
            for (int mi = 0; mi < 4; ++mi)
#pragma unroll
                for (int ni = 0; ni < 4; ++ni)
                    acc[mi][ni] = __builtin_amdgcn_mfma_f32_16x16x32_bf16(ah[mi], bh[ni], acc[mi][ni], 0, 0, 0);
            bf16x8 al[4];
#pragma unroll
            for (int mi = 0; mi < 4; ++mi) {
                const int r = wr * 64 + mi * 16 + (lane & 15);
                al[mi] = *(const bf16x8*)(smem + 16384 + r * 128 + (cb ^ ((r & 7) << 4)));
            }
#pragma unroll
            for (int mi = 0; mi < 4; ++mi)
#pragma unroll
                for (int ni = 0; ni < 4; ++ni)
                    acc[mi][ni] = __builtin_amdgcn_mfma_f32_16x16x32_bf16(al[mi], bh[ni], acc[mi][ni], 0, 0, 0);
            bf16x8 bl[4];
#pragma unroll
            for (int ni = 0; ni < 4; ++ni) {
                const int r = wc * 64 + ni * 16 + (lane & 15);
                bl[ni] = *(const bf16x8*)(smem + 49152 + r * 128 + (cb ^ ((r & 7) << 4)));
            }
#pragma unroll
            for (int mi = 0; mi < 4; ++mi)
#pragma unroll
                for (int ni = 0; ni < 4; ++ni)
                    acc[mi][ni] = __builtin_amdgcn_mfma_f32_16x16x32_bf16(ah[mi], bl[ni], acc[mi][ni], 0, 0, 0);
        }
    }

    // epilogue: bias + store (C/D layout: col=lane&15, row=(lane>>4)*4+j)
#pragma unroll
    for (int ni = 0; ni < 4; ++ni) {
        const int col = col0 + wc * 64 + ni * 16 + (lane & 15);
        const float bz = bias[col];
#pragma unroll
        for (int mi = 0; mi < 4; ++mi) {
            const int rbase = row0 + wr * 64 + mi * 16 + ((lane >> 4) << 2);
            const f32x4 v = acc[mi][ni];
#pragma unroll
            for (int j = 0; j < 4; ++j) {
                const float val = v[j] + bz;
                if (store_bf16)
                    ((unsigned short*)outp)[(size_t)(rbase + j) * DDIM + col] = f2bf(val);
                else
                    ((float*)outp)[(size_t)(rbase + j) * DDIM + col] = val;
            }
        }
    }
}

// ---------------- Kernel D: per-token 8-head attention over 16 retrieved slots ----------------
__global__ __launch_bounds__(256)
void attn_kernel(const float* __restrict__ Qp, const __hip_bfloat16* __restrict__ Kp,
                 const __hip_bfloat16* __restrict__ Vp, const int* __restrict__ topk,
                 float* __restrict__ attn_out)
{
    const int t = blockIdx.x;
    __shared__ int   idx_s[KSEL];
    __shared__ float sc_s[4][KSEL];
    if (threadIdx.x < KSEL) idx_s[threadIdx.x] = topk[(size_t)t * KSEL + threadIdx.x];
    __syncthreads();
    const int wv   = threadIdx.x >> 6;
    const int lane = threadIdx.x & 63;
    const int jj = lane >> 2, p = lane & 3;
    const float scale = 0.08838834764831845f;  // 1/sqrt(128)
    const unsigned short* Kpu = (const unsigned short*)Kp;
    const unsigned short* Vpu = (const unsigned short*)Vp;

#pragma unroll 1
    for (int hh = 0; hh < 2; ++hh) {
        const int h = wv * 2 + hh;
        const float* qh = Qp + (size_t)t * DDIM + h * HDIM + p * 32;
        const unsigned short* krow = Kpu + (size_t)idx_s[jj] * DDIM + h * HDIM + p * 32;
        float s = 0.f;
#pragma unroll
        for (int u = 0; u < 32; u += 8) {
            uint4  kv = *(const uint4*)(krow + u);
            float4 qa = *(const float4*)(qh + u);
            float4 qb = *(const float4*)(qh + u + 4);
            const unsigned short* kk = (const unsigned short*)&kv;
            s += bf2f(kk[0]) * qa.x + bf2f(kk[1]) * qa.y + bf2f(kk[2]) * qa.z + bf2f(kk[3]) * qa.w
               + bf2f(kk[4]) * qb.x + bf2f(kk[5]) * qb.y + bf2f(kk[6]) * qb.z + bf2f(kk[7]) * qb.w;
        }
        s += __shfl_xor(s, 1);
        s += __shfl_xor(s, 2);
        if (p == 0) sc_s[wv][jj] = s * scale;
        __syncthreads();
        float mx = -__builtin_inff();
#pragma unroll
        for (int n = 0; n < KSEL; ++n) mx = fmaxf(mx, sc_s[wv][n]);
        float wj[KSEL]; float wsum = 0.f;
#pragma unroll
        for (int n = 0; n < KSEL; ++n) { wj[n] = __expf(sc_s[wv][n] - mx); wsum += wj[n]; }
        const float inv = 1.f / wsum;
        const int d = lane * 2;
        float o0 = 0.f, o1 = 0.f;
#pragma unroll
        for (int n = 0; n < KSEL; ++n) {
            const unsigned int vv = *(const unsigned int*)(Vpu + (size_t)idx_s[n] * DDIM + h * HDIM + d);
            const float w = wj[n] * inv;
            o0 += w * bf2f((unsigned short)(vv & 0xffffu));
            o1 += w * bf2f((unsigned short)(vv >> 16));
        }
        *(float2*)(attn_out + (size_t)t * DDIM + h * HDIM + d) = make_float2(o0, o1);
        __syncthreads();
    }
}

extern "C" void kernel_launch(void* const* d_in, const int* in_sizes, int n_in,
                              void* d_out, int out_size, void* d_ws, size_t ws_size,
                              hipStream_t stream)
{
    const float* queries = (const float*)d_in[0];
    const float* mkeys   = (const float*)d_in[1];
    const float* mvals   = (const float*)d_in[2];
    const float* ipw     = (const float*)d_in[3];
    const float* ipb     = (const float*)d_in[4];
    const float* opw     = (const float*)d_in[5];
    const float* opb     = (const float*)d_in[6];

    char* ws = (char*)d_ws;
    size_t off = 0;
    auto alloc = [&](size_t bytes) -> char* {
        char* p = ws + off;
        off += (bytes + 255) & ~(size_t)255;
        return p;
    };
    unsigned short* Khi = (unsigned short*)alloc((size_t)MKEYS * DDIM * 2);   // 67.1 MB
    unsigned short* Klo = (unsigned short*)alloc((size_t)MKEYS * DDIM * 2);   // 67.1 MB
    unsigned short* Qhi = (unsigned short*)alloc((size_t)NROWS * DDIM * 2);   // 8.4 MB
    unsigned short* Qlo = (unsigned short*)alloc((size_t)NROWS * DDIM * 2);   // 8.4 MB
    unsigned short* IPhi = (unsigned short*)alloc((size_t)3 * DDIM * DDIM * 2); // 6.3 MB
    unsigned short* IPlo = (unsigned short*)alloc((size_t)3 * DDIM * DDIM * 2); // 6.3 MB
    unsigned short* OPhi = (unsigned short*)alloc((size_t)DDIM * DDIM * 2);     // 2.1 MB
    unsigned short* OPlo = (unsigned short*)alloc((size_t)DDIM * DDIM * 2);     // 2.1 MB
    float* cand_val = (float*)alloc((size_t)NROWS * CANDS_PER_ROW * 4);       // 33.5 MB
    int*   cand_idx = (int*)  alloc((size_t)NROWS * CANDS_PER_ROW * 4);       // 33.5 MB
    int*   topk     = (int*)  alloc((size_t)NROWS * KSEL * 4);                // 0.26 MB
    // stream-ordered aliases (total ws ~235 MB):
    float* Qp       = (float*)cand_val;            // written after merge
    float* attn_out = (float*)cand_idx;            // written by attn (after merge)
    __hip_bfloat16* Kp = (__hip_bfloat16*)Khi;     // K-proj reads mkeys(fp32), Khi dead after sims
    __hip_bfloat16* Vp = (__hip_bfloat16*)Klo;

    // 0) splits: sims operands + weights
    split_bf16_kernel<<<2048, 256, 0, stream>>>(queries, Qhi, Qlo, NROWS * DDIM / 4);
    split_bf16_kernel<<<2048, 256, 0, stream>>>(mkeys, Khi, Klo, MKEYS * DDIM / 4);
    split_bf16_kernel<<<1024, 256, 0, stream>>>(ipw, IPhi, IPlo, 3 * DDIM * DDIM / 4);
    split_bf16_kernel<<<512,  256, 0, stream>>>(opw, OPhi, OPlo, DDIM * DDIM / 4);
    // 1) similarity GEMM (split-bf16 MFMA) + per-keyblock top-16
    sims_mfma_kernel<<<dim3(NROWS / SBM, MKEYS / SBN), 256, 0, stream>>>(Qhi, Qlo, Khi, Klo, cand_val, cand_idx);
    // 2) merge to global top-16 indices
    topk_merge_kernel<<<NROWS / 4, 256, 0, stream>>>(cand_val, cand_idx, topk);
    // 3) projections (split-bf16 MFMA): q (f32 out), memory bank through Wk/Wv (bf16 out)
    proj_split_kernel<<<dim3(NROWS / 128, 8), 256, 0, stream>>>(queries, IPhi, IPlo, ipb, Qp, 0);
    proj_split_kernel<<<dim3(MKEYS / 128, 8), 256, 0, stream>>>(mkeys, IPhi + (size_t)DDIM * DDIM,
                                                                IPlo + (size_t)DDIM * DDIM, ipb + DDIM, Kp, 1);
    proj_split_kernel<<<dim3(MKEYS / 128, 8), 256, 0, stream>>>(mvals, IPhi + 2 * (size_t)DDIM * DDIM,
                                                                IPlo + 2 * (size_t)DDIM * DDIM, ipb + 2 * DDIM, Vp, 1);
    // 4) gather + attention
    attn_kernel<<<NROWS, 256, 0, stream>>>(Qp, Kp, Vp, topk, attn_out);
    // 5) output projection -> d_out (f32)
    proj_split_kernel<<<dim3(NROWS / 128, 8), 256, 0, stream>>>(attn_out, OPhi, OPlo, opb, d_out, 0);
}

// Round 4
// 2217.224 us; speedup vs baseline: 9.5176x; 1.5272x over previous
//
#include <hip/hip_runtime.h>
#include <hip/hip_bf16.h>

#define NROWS 4096    // B*S
#define DDIM  1024
#define MKEYS 32768
#define HDIM  128
#define KSEL  16

// ---- sims MFMA GEMM geometry: 256x256 tile, 8 waves, double-buffered ----
#define SBM 256            // rows per block
#define SBN 256            // keys per block
#define SNKB (MKEYS / SBN) // 128 key blocks
#define CANDS_PER_ROW (SNKB * KSEL)   // 2048

typedef short bf16x8 __attribute__((ext_vector_type(8)));
typedef float f32x4  __attribute__((ext_vector_type(4)));

__device__ __forceinline__ float bf2f(unsigned short u) {
    union { unsigned int i; float f; } x; x.i = ((unsigned int)u) << 16; return x.f;
}
__device__ __forceinline__ unsigned short f2bf(float f) {
    union { float f; unsigned int u; } v; v.f = f;
    unsigned int r = (v.u + 0x7fffu + ((v.u >> 16) & 1u)) >> 16;   // RNE
    return (unsigned short)r;
}
__device__ __forceinline__ void gload16(const void* g, const void* l) {
    __builtin_amdgcn_global_load_lds((const __attribute__((address_space(1))) unsigned int*)g,
                                     (__attribute__((address_space(3))) unsigned int*)l, 16, 0, 0);
}
// sorted-descending top-16 insertion, fully static indexing (no scratch)
__device__ __forceinline__ void ins16(float v, int id, float* lv, int* li) {
    if (v > lv[15]) {
#pragma unroll
        for (int i = 0; i < 16; ++i) {
            const bool gt = v > lv[i];
            const float tv = gt ? lv[i] : v;
            const int   ti = gt ? li[i] : id;
            if (gt) { lv[i] = v; li[i] = id; }
            v = tv; id = ti;
        }
    }
}
// trunc-hi / RNE-lo split of two fp32 -> packed bf16 pair words
__device__ __forceinline__ void split2(float x0, float x1, unsigned int& hp, unsigned int& lp) {
    union { float f; unsigned int u; } u0, u1;
    u0.f = x0; u1.f = x1;
    hp = (u0.u >> 16) | (u1.u & 0xffff0000u);
    const float r0 = x0 - bf2f((unsigned short)(u0.u >> 16));
    const float r1 = x1 - bf2f((unsigned short)(u1.u >> 16));
    lp = (unsigned int)f2bf(r0) | ((unsigned int)f2bf(r1) << 16);
}

// ---------------- Kernel 0: fp32 -> (hi, lo) bf16 split ----------------
__global__ __launch_bounds__(256)
void split_bf16_kernel(const float* __restrict__ x, unsigned short* __restrict__ hi,
                       unsigned short* __restrict__ lo, const int n4)
{
    int i = blockIdx.x * 256 + threadIdx.x;
    const int stride = gridDim.x * 256;
    for (; i < n4; i += stride) {
        const float4 f = ((const float4*)x)[i];
        ushort4 h, l;
        h.x = f2bf(f.x); l.x = f2bf(f.x - bf2f(h.x));
        h.y = f2bf(f.y); l.y = f2bf(f.y - bf2f(h.y));
        h.z = f2bf(f.z); l.z = f2bf(f.z - bf2f(h.z));
        h.w = f2bf(f.w); l.w = f2bf(f.w - bf2f(h.w));
        ((ushort4*)hi)[i] = h;
        ((ushort4*)lo)[i] = l;
    }
}

// ---------------- Kernel A: sims = Q.K^T, 256x256 dbuf counted-vmcnt MFMA + fused top-16 ----------------
// 8 waves as 2x4: wrow=w>>2 (rows wrow*128 + mi*16, mi 0..7), wcol=w&3 (cols wcol*64 + ni*16, ni 0..3).
// LDS: 2 buffers of 64KB; per buffer A[256][64]bf16 @0 (32KB), B[256][64]bf16 @32KB.
// Logical K = 3 segments x 1024: (Qhi,Khi),(Qlo,Khi),(Qhi,Klo).
// Pipeline: STAGE(next) -> vmcnt(8) -> s_barrier -> ds_read+MFMA(cur) -> lgkmcnt(0)+s_barrier.
__global__ __launch_bounds__(512, 2)
void sims_mfma_kernel(const unsigned short* __restrict__ Qhi, const unsigned short* __restrict__ Qlo,
                      const unsigned short* __restrict__ Khi, const unsigned short* __restrict__ Klo,
                      float* __restrict__ cand_val, int* __restrict__ cand_idx)
{
    __shared__ char smem[131072];
    const int tid  = threadIdx.x;
    const int lane = tid & 63;
    const int w    = tid >> 6;
    const int wrow = w >> 2, wcol = w & 3;
    const int row0 = blockIdx.x * SBM;
    const int key0 = blockIdx.y * SBN;

    const f32x4 zero = {0.f, 0.f, 0.f, 0.f};
    f32x4 acc[8][4];
#pragma unroll
    for (int mi = 0; mi < 8; ++mi)
#pragma unroll
        for (int ni = 0; ni < 4; ++ni) acc[mi][ni] = zero;

    const int srow = lane >> 3;                                   // row within 8-row chunk
    const int scol = (((lane & 7) ^ srow) << 4);                  // pre-swizzled source byte col [0,128)

    // stage one 64-K-element tile pair (A 32KB + B 32KB) into buffer b; 8 gloads/thread
    auto STAGE = [&](int b, int s) {
        const int seg   = s >> 4;
        const int kbyte = (s & 15) << 7;                          // 128B per K-step
        const unsigned short* Ab = (seg == 1) ? Qlo : Qhi;
        const unsigned short* Bb = (seg == 2) ? Klo : Khi;
        char* dst = smem + (b << 16);
#pragma unroll
        for (int i = 0; i < 8; ++i) {
            const int chunk = w + (i << 3);                       // 0..63, wave-uniform
            const char* src;
            if (chunk < 32) {                                     // A: rows 0..255
                const int r = (chunk << 3) + srow;
                src = (const char*)Ab + (((size_t)(row0 + r)) << 11) + kbyte + scol;
            } else {                                              // B: keys 0..255
                const int r = ((chunk - 32) << 3) + srow;
                src = (const char*)Bb + (((size_t)(key0 + r)) << 11) + kbyte + scol;
            }
            gload16(src, dst + (chunk << 10));
        }
    };

    STAGE(0, 0);
    int cur = 0;
#pragma unroll 1
    for (int step = 0; step < 48; ++step) {
        if (step + 1 < 48) {
            STAGE(cur ^ 1, step + 1);                             // prefetch next K-tile
            asm volatile("s_waitcnt vmcnt(8)\n\ts_barrier" ::: "memory");   // cur's 8 loads done; 8 stay in flight
        } else {
            asm volatile("s_waitcnt vmcnt(0)\n\ts_barrier" ::: "memory");
        }
        const char* Abuf = smem + (cur << 16);
        const char* Bbuf = Abuf + 32768;
#pragma unroll
        for (int kk = 0; kk < 2; ++kk) {
            const int cb = (kk << 6) + ((lane >> 4) << 4);
            bf16x8 af[8], bf[4];
#pragma unroll
            for (int mi = 0; mi < 8; ++mi) {
                const int r = wrow * 128 + mi * 16 + (lane & 15);
                af[mi] = *(const bf16x8*)(Abuf + r * 128 + (cb ^ ((r & 7) << 4)));
            }
#pragma unroll
            for (int ni = 0; ni < 4; ++ni) {
                const int r = wcol * 64 + ni * 16 + (lane & 15);
                bf[ni] = *(const bf16x8*)(Bbuf + r * 128 + (cb ^ ((r & 7) << 4)));
            }
#pragma unroll
            for (int mi = 0; mi < 8; ++mi)
#pragma unroll
                for (int ni = 0; ni < 4; ++ni)
                    acc[mi][ni] = __builtin_amdgcn_mfma_f32_16x16x32_bf16(af[mi], bf[ni], acc[mi][ni], 0, 0, 0);
        }
        asm volatile("s_waitcnt lgkmcnt(0)\n\ts_barrier" ::: "memory");     // reads retired -> buffer reusable
        cur ^= 1;
    }

    // ---- fused top-16 epilogue: 4 quarter-passes of 64 cols through LDS C tile [256][68] f32 ----
    float lv[16]; int li[16];
#pragma unroll
    for (int i = 0; i < 16; ++i) { lv[i] = -3.4e38f; li[i] = 0; }
    float* C_lds = (float*)smem;

#pragma unroll
    for (int q = 0; q < 4; ++q) {
        __syncthreads();
        if (wcol == q) {                                          // 2 waves dump their 128x64 quarters
#pragma unroll
            for (int mi = 0; mi < 8; ++mi)
#pragma unroll
                for (int ni = 0; ni < 4; ++ni) {
                    const int r = wrow * 128 + mi * 16 + ((lane >> 4) << 2);
                    const int c = ni * 16 + (lane & 15);
                    const f32x4 v = acc[mi][ni];
#pragma unroll
                    for (int j = 0; j < 4; ++j) C_lds[(r + j) * 68 + c] = v[j];
                }
        }
        __syncthreads();
        if (tid < 256) {                                          // thread t scans row t
            const int gbase = key0 + (q << 6);
#pragma unroll 1
            for (int c4 = 0; c4 < 16; ++c4) {
                const float4 vv = *(const float4*)&C_lds[tid * 68 + (c4 << 2)];
                const float thr = lv[15];
                if (vv.x > thr || vv.y > thr || vv.z > thr || vv.w > thr) {
                    ins16(vv.x, gbase + c4 * 4 + 0, lv, li);
                    ins16(vv.y, gbase + c4 * 4 + 1, lv, li);
                    ins16(vv.z, gbase + c4 * 4 + 2, lv, li);
                    ins16(vv.w, gbase + c4 * 4 + 3, lv, li);
                }
            }
        }
    }
    if (tid < 256) {
        const size_t o = (((size_t)(row0 + tid)) * SNKB + blockIdx.y) * KSEL;
#pragma unroll
        for (int i = 0; i < 16; ++i) { cand_val[o + i] = lv[i]; cand_idx[o + i] = li[i]; }
    }
}

// ---------------- Kernel B: merge 128 blocks x 16 candidates -> global top-16 per row ----------------
__global__ __launch_bounds__(256)
void topk_merge_kernel(const float* __restrict__ cand_val, const int* __restrict__ cand_idx,
                       int* __restrict__ topk)
{
    const int row  = blockIdx.x * 4 + (threadIdx.x >> 6);
    const int lane = threadIdx.x & 63;
    const size_t base = (size_t)row * CANDS_PER_ROW;
    float lv[16]; int li[16];
#pragma unroll
    for (int i = 0; i < 16; ++i) { lv[i] = -3.4e38f; li[i] = 0x7fffffff; }
#pragma unroll 1
    for (int m = 0; m < CANDS_PER_ROW / 64; ++m) {                // 32 per lane
        const int p = lane + (m << 6);
        ins16(cand_val[base + p], cand_idx[base + p], lv, li);
    }
    int out = 0;
#pragma unroll 1
    for (int it = 0; it < KSEL; ++it) {
        float rv = lv[0]; int ridx = li[0];
#pragma unroll
        for (int off = 1; off < 64; off <<= 1) {
            const float ov = __shfl_xor(rv, off);
            const int   oi = __shfl_xor(ridx, off);
            if (ov > rv || (ov == rv && oi < ridx)) { rv = ov; ridx = oi; }
        }
        if (lane == it) out = ridx;
        if (li[0] == ridx) {
#pragma unroll
            for (int i = 0; i < 15; ++i) { lv[i] = lv[i + 1]; li[i] = li[i + 1]; }
            lv[15] = -3.4e38f; li[15] = 0x7fffffff;
        }
    }
    if (lane < KSEL) topk[(size_t)row * KSEL + lane] = out;
}

// ---------------- Kernel C: projections via split-bf16 MFMA (unchanged, known-good) ----------------
__global__ __launch_bounds__(256)
void proj_split_kernel(const float* __restrict__ X, const unsigned short* __restrict__ Whi,
                       const unsigned short* __restrict__ Wlo, const float* __restrict__ bias,
                       void* __restrict__ outp, const int store_bf16)
{
    __shared__ char smem[65536];
    const int tid  = threadIdx.x;
    const int lane = tid & 63;
    const int w    = tid >> 6;
    const int wr   = w >> 1, wc = w & 1;
    const int row0 = blockIdx.x * 128;
    const int col0 = blockIdx.y * 128;

    const f32x4 zero = {0.f, 0.f, 0.f, 0.f};
    f32x4 acc[4][4];
#pragma unroll
    for (int mi = 0; mi < 4; ++mi)
#pragma unroll
        for (int ni = 0; ni < 4; ++ni) acc[mi][ni] = zero;

    const int srow = lane >> 3;
    const int scol = (((lane & 7) ^ srow) << 4);
    const int xr = tid >> 1, xh = tid & 1;

    for (int step = 0; step < 16; ++step) {
        const int kbyte = step << 7;
        const int k0    = step << 6;
        __syncthreads();
#pragma unroll
        for (int i = 0; i < 8; ++i) {
            const int chunk = w + (i << 2);
            const int plane = chunk >> 4;
            const int r     = ((chunk & 15) << 3) + srow;
            const unsigned short* Wb = plane ? Wlo : Whi;
            const char* src = (const char*)Wb + (((size_t)(col0 + r)) << 11) + kbyte + scol;
            gload16(src, smem + 32768 + (chunk << 10));
        }
        {
            const float* Xp = X + (size_t)(row0 + xr) * DDIM + k0 + xh * 32;
            float4 xa[8];
#pragma unroll
            for (int i = 0; i < 8; ++i) xa[i] = ((const float4*)Xp)[i];
            const int xbase = xr * 128;
#pragma unroll
            for (int s4 = 0; s4 < 4; ++s4) {
                const float4 a = xa[2 * s4], b = xa[2 * s4 + 1];
                uint4 hw, lw;
                split2(a.x, a.y, hw.x, lw.x);
                split2(a.z, a.w, hw.y, lw.y);
                split2(b.x, b.y, hw.z, lw.z);
                split2(b.z, b.w, hw.w, lw.w);
                const int off = xbase + ((((xh << 2) + s4) ^ (xr & 7)) << 4);
                *(uint4*)(smem + off)         = hw;
                *(uint4*)(smem + 16384 + off) = lw;
            }
        }
        asm volatile("s_waitcnt vmcnt(0)" ::: "memory");
        __syncthreads();
#pragma unroll
        for (int kk = 0; kk < 2; ++kk) {
            const int cb = (kk << 6) + ((lane >> 4) << 4);
            bf16x8 ah[4], bh[4];
#pragma unroll
            for (int mi = 0; mi < 4; ++mi) {
                const int r = wr * 64 + mi * 16 + (lane & 15);
                ah[mi] = *(const bf16x8*)(smem + r * 128 + (cb ^ ((r & 7) << 4)));
            }
#pragma unroll
            for (int ni = 0; ni < 4; ++ni) {
                const int r = wc * 64 + ni * 16 + (lane & 15);
                bh[ni] = *(const bf16x8*)(smem + 32768 + r * 128 + (cb ^ ((r & 7) << 4)));
            }
#pragma unroll
            for (int mi = 0; mi < 4; ++mi)
#pragma unroll
                for (int ni = 0; ni < 4; ++ni)
                    acc[mi][ni] = __builtin_amdgcn_mfma_f32_16x16x32_bf16(ah[mi], bh[ni], acc[mi][ni], 0, 0, 0);
            bf16x8 al[4];
#pragma unroll
            for (int mi = 0; mi < 4; ++mi) {
                const int r = wr * 64 + mi * 16 + (lane & 15);
                al[mi] = *(const bf16x8*)(smem + 16384 + r * 128 + (cb ^ ((r & 7) << 4)));
            }
#pragma unroll
            for (int mi = 0; mi < 4; ++mi)
#pragma unroll
                for (int ni = 0; ni < 4; ++ni)
                    acc[mi][ni] = __builtin_amdgcn_mfma_f32_16x16x32_bf16(al[mi], bh[ni], acc[mi][ni], 0, 0, 0);
            bf16x8 bl[4];
#pragma unroll
            for (int ni = 0; ni < 4; ++ni) {
                const int r = wc * 64 + ni * 16 + (lane & 15);
                bl[ni] = *(const bf16x8*)(smem + 49152 + r * 128 + (cb ^ ((r & 7) << 4)));
            }
#pragma unroll
            for (int mi = 0; mi < 4; ++mi)
#pragma unroll
                for (int ni = 0; ni < 4; ++ni)
                    acc[mi][ni] = __builtin_amdgcn_mfma_f32_16x16x32_bf16(ah[mi], bl[ni], acc[mi][ni], 0, 0, 0);
        }
    }

#pragma unroll
    for (int ni = 0; ni < 4; ++ni) {
        const int col = col0 + wc * 64 + ni * 16 + (lane & 15);
        const float bz = bias[col];
#pragma unroll
        for (int mi = 0; mi < 4; ++mi) {
            const int rbase = row0 + wr * 64 + mi * 16 + ((lane >> 4) << 2);
            const f32x4 v = acc[mi][ni];
#pragma unroll
            for (int j = 0; j < 4; ++j) {
                const float val = v[j] + bz;
                if (store_bf16)
                    ((unsigned short*)outp)[(size_t)(rbase + j) * DDIM + col] = f2bf(val);
                else
                    ((float*)outp)[(size_t)(rbase + j) * DDIM + col] = val;
            }
        }
    }
}

// ---------------- Kernel D: per-token 8-head attention over 16 retrieved slots ----------------
__global__ __launch_bounds__(256)
void attn_kernel(const float* __restrict__ Qp, const __hip_bfloat16* __restrict__ Kp,
                 const __hip_bfloat16* __restrict__ Vp, const int* __restrict__ topk,
                 float* __restrict__ attn_out)
{
    const int t = blockIdx.x;
    __shared__ int   idx_s[KSEL];
    __shared__ float sc_s[4][KSEL];
    if (threadIdx.x < KSEL) idx_s[threadIdx.x] = topk[(size_t)t * KSEL + threadIdx.x];
    __syncthreads();
    const int wv   = threadIdx.x >> 6;
    const int lane = threadIdx.x & 63;
    const int jj = lane >> 2, p = lane & 3;
    const float scale = 0.08838834764831845f;  // 1/sqrt(128)
    const unsigned short* Kpu = (const unsigned short*)Kp;
    const unsigned short* Vpu = (const unsigned short*)Vp;

#pragma unroll 1
    for (int hh = 0; hh < 2; ++hh) {
        const int h = wv * 2 + hh;
        const float* qh = Qp + (size_t)t * DDIM + h * HDIM + p * 32;
        const unsigned short* krow = Kpu + (size_t)idx_s[jj] * DDIM + h * HDIM + p * 32;
        float s = 0.f;
#pragma unroll
        for (int u = 0; u < 32; u += 8) {
            uint4  kv = *(const uint4*)(krow + u);
            float4 qa = *(const float4*)(qh + u);
            float4 qb = *(const float4*)(qh + u + 4);
            const unsigned short* kk = (const unsigned short*)&kv;
            s += bf2f(kk[0]) * qa.x + bf2f(kk[1]) * qa.y + bf2f(kk[2]) * qa.z + bf2f(kk[3]) * qa.w
               + bf2f(kk[4]) * qb.x + bf2f(kk[5]) * qb.y + bf2f(kk[6]) * qb.z + bf2f(kk[7]) * qb.w;
        }
        s += __shfl_xor(s, 1);
        s += __shfl_xor(s, 2);
        if (p == 0) sc_s[wv][jj] = s * scale;
        __syncthreads();
        float mx = -__builtin_inff();
#pragma unroll
        for (int n = 0; n < KSEL; ++n) mx = fmaxf(mx, sc_s[wv][n]);
        float wj[KSEL]; float wsum = 0.f;
#pragma unroll
        for (int n = 0; n < KSEL; ++n) { wj[n] = __expf(sc_s[wv][n] - mx); wsum += wj[n]; }
        const float inv = 1.f / wsum;
        const int d = lane * 2;
        float o0 = 0.f, o1 = 0.f;
#pragma unroll
        for (int n = 0; n < KSEL; ++n) {
            const unsigned int vv = *(const unsigned int*)(Vpu + (size_t)idx_s[n] * DDIM + h * HDIM + d);
            const float w = wj[n] * inv;
            o0 += w * bf2f((unsigned short)(vv & 0xffffu));
            o1 += w * bf2f((unsigned short)(vv >> 16));
        }
        *(float2*)(attn_out + (size_t)t * DDIM + h * HDIM + d) = make_float2(o0, o1);
        __syncthreads();
    }
}

extern "C" void kernel_launch(void* const* d_in, const int* in_sizes, int n_in,
                              void* d_out, int out_size, void* d_ws, size_t ws_size,
                              hipStream_t stream)
{
    const float* queries = (const float*)d_in[0];
    const float* mkeys   = (const float*)d_in[1];
    const float* mvals   = (const float*)d_in[2];
    const float* ipw     = (const float*)d_in[3];
    const float* ipb     = (const float*)d_in[4];
    const float* opw     = (const float*)d_in[5];
    const float* opb     = (const float*)d_in[6];

    char* ws = (char*)d_ws;
    size_t off = 0;
    auto alloc = [&](size_t bytes) -> char* {
        char* p = ws + off;
        off += (bytes + 255) & ~(size_t)255;
        return p;
    };
    unsigned short* Khi = (unsigned short*)alloc((size_t)MKEYS * DDIM * 2);   // 67.1 MB
    unsigned short* Klo = (unsigned short*)alloc((size_t)MKEYS * DDIM * 2);   // 67.1 MB
    unsigned short* Qhi = (unsigned short*)alloc((size_t)NROWS * DDIM * 2);   // 8.4 MB
    unsigned short* Qlo = (unsigned short*)alloc((size_t)NROWS * DDIM * 2);   // 8.4 MB
    unsigned short* IPhi = (unsigned short*)alloc((size_t)3 * DDIM * DDIM * 2); // 6.3 MB
    unsigned short* IPlo = (unsigned short*)alloc((size_t)3 * DDIM * DDIM * 2); // 6.3 MB
    unsigned short* OPhi = (unsigned short*)alloc((size_t)DDIM * DDIM * 2);     // 2.1 MB
    unsigned short* OPlo = (unsigned short*)alloc((size_t)DDIM * DDIM * 2);     // 2.1 MB
    float* cand_val = (float*)alloc((size_t)NROWS * CANDS_PER_ROW * 4);       // 33.5 MB
    int*   cand_idx = (int*)  alloc((size_t)NROWS * CANDS_PER_ROW * 4);       // 33.5 MB
    int*   topk     = (int*)  alloc((size_t)NROWS * KSEL * 4);                // 0.26 MB
    // stream-ordered aliases (total ws ~235 MB):
    float* Qp       = (float*)cand_val;            // written after merge
    float* attn_out = (float*)cand_idx;            // written by attn (after merge)
    __hip_bfloat16* Kp = (__hip_bfloat16*)Khi;     // Khi/Klo dead after sims
    __hip_bfloat16* Vp = (__hip_bfloat16*)Klo;

    // 0) splits: sims operands + weights
    split_bf16_kernel<<<2048, 256, 0, stream>>>(queries, Qhi, Qlo, NROWS * DDIM / 4);
    split_bf16_kernel<<<2048, 256, 0, stream>>>(mkeys, Khi, Klo, MKEYS * DDIM / 4);
    split_bf16_kernel<<<1024, 256, 0, stream>>>(ipw, IPhi, IPlo, 3 * DDIM * DDIM / 4);
    split_bf16_kernel<<<512,  256, 0, stream>>>(opw, OPhi, OPlo, DDIM * DDIM / 4);
    // 1) similarity GEMM (split-bf16 MFMA, dbuf counted-vmcnt) + per-keyblock top-16
    sims_mfma_kernel<<<dim3(NROWS / SBM, MKEYS / SBN), 512, 0, stream>>>(Qhi, Qlo, Khi, Klo, cand_val, cand_idx);
    // 2) merge to global top-16 indices
    topk_merge_kernel<<<NROWS / 4, 256, 0, stream>>>(cand_val, cand_idx, topk);
    // 3) projections (split-bf16 MFMA): q (f32 out), memory bank through Wk/Wv (bf16 out)
    proj_split_kernel<<<dim3(NROWS / 128, 8), 256, 0, stream>>>(queries, IPhi, IPlo, ipb, Qp, 0);
    proj_split_kernel<<<dim3(MKEYS / 128, 8), 256, 0, stream>>>(mkeys, IPhi + (size_t)DDIM * DDIM,
                                                                IPlo + (size_t)DDIM * DDIM, ipb + DDIM, Kp, 1);
    proj_split_kernel<<<dim3(MKEYS / 128, 8), 256, 0, stream>>>(mvals, IPhi + 2 * (size_t)DDIM * DDIM,
                                                                IPlo + 2 * (size_t)DDIM * DDIM, ipb + 2 * DDIM, Vp, 1);
    // 4) gather + attention
    attn_kernel<<<NROWS, 256, 0, stream>>>(Qp, Kp, Vp, topk, attn_out);
    // 5) output projection -> d_out (f32)
    proj_split_kernel<<<dim3(NROWS / 128, 8), 256, 0, stream>>>(attn_out, OPhi, OPlo, opb, d_out, 0);
}